// Round 2
// baseline (31.653 us; speedup 1.0000x reference)
//
#include <hip/hip_runtime.h>

#define LDIM 16
#define CDIM 3
#define HW (512 * 512)
#define NCH (LDIM * CDIM)   // 48 channels
#define BPC 32              // blocks per channel -> 1536 blocks = 6/CU exactly
#define TPB 256
#define ITERS (HW / 4 / (BPC * TPB))  // = 8, exact
#define V_EPS 1e-5

// Kernel 1: per-block partial sums of {e*e*m, c*e*m, c*c*m, m} over one channel.
__global__ __launch_bounds__(TPB) void smse_partials(
    const float* __restrict__ correct,
    const float* __restrict__ estimate,
    const float* __restrict__ mask,
    float4* __restrict__ partials)  // [NCH * BPC]
{
    const int ch  = blockIdx.x / BPC;
    const int bin = blockIdx.x % BPC;

    const float4* __restrict__ c4 = (const float4*)(correct  + (size_t)ch * HW);
    const float4* __restrict__ e4 = (const float4*)(estimate + (size_t)ch * HW);
    const float4* __restrict__ m4 = (const float4*)(mask     + (size_t)ch * HW);

    const int stride = BPC * TPB;                 // 8192 float4
    int i = bin * TPB + threadIdx.x;

    float se2m_a = 0.f, scem_a = 0.f, sc2m_a = 0.f, sm_a = 0.f;
    float se2m_b = 0.f, scem_b = 0.f, sc2m_b = 0.f, sm_b = 0.f;

    #pragma unroll
    for (int it = 0; it < ITERS / 2; ++it) {
        // Issue all 6 loads before any dependent compute (MLP).
        float4 c0 = c4[i];
        float4 e0 = e4[i];
        float4 m0 = m4[i];
        float4 c1 = c4[i + stride];
        float4 e1 = e4[i + stride];
        float4 m1 = m4[i + stride];
        i += 2 * stride;

        float em;
        em = e0.x * m0.x; se2m_a += e0.x * em; scem_a += c0.x * em;
        sc2m_a += c0.x * c0.x * m0.x; sm_a += m0.x;
        em = e0.y * m0.y; se2m_a += e0.y * em; scem_a += c0.y * em;
        sc2m_a += c0.y * c0.y * m0.y; sm_a += m0.y;
        em = e0.z * m0.z; se2m_a += e0.z * em; scem_a += c0.z * em;
        sc2m_a += c0.z * c0.z * m0.z; sm_a += m0.z;
        em = e0.w * m0.w; se2m_a += e0.w * em; scem_a += c0.w * em;
        sc2m_a += c0.w * c0.w * m0.w; sm_a += m0.w;

        em = e1.x * m1.x; se2m_b += e1.x * em; scem_b += c1.x * em;
        sc2m_b += c1.x * c1.x * m1.x; sm_b += m1.x;
        em = e1.y * m1.y; se2m_b += e1.y * em; scem_b += c1.y * em;
        sc2m_b += c1.y * c1.y * m1.y; sm_b += m1.y;
        em = e1.z * m1.z; se2m_b += e1.z * em; scem_b += c1.z * em;
        sc2m_b += c1.z * c1.z * m1.z; sm_b += m1.z;
        em = e1.w * m1.w; se2m_b += e1.w * em; scem_b += c1.w * em;
        sc2m_b += c1.w * c1.w * m1.w; sm_b += m1.w;
    }

    float se2m = se2m_a + se2m_b;
    float scem = scem_a + scem_b;
    float sc2m = sc2m_a + sc2m_b;
    float sm   = sm_a + sm_b;

    // Wave64 butterfly reduce of the 4 accumulators.
    #pragma unroll
    for (int off = 32; off > 0; off >>= 1) {
        se2m += __shfl_down(se2m, off);
        scem += __shfl_down(scem, off);
        sc2m += __shfl_down(sc2m, off);
        sm   += __shfl_down(sm,   off);
    }

    __shared__ float4 red[TPB / 64];  // one float4 per wave
    const int wave = threadIdx.x >> 6;
    const int lane = threadIdx.x & 63;
    if (lane == 0) red[wave] = make_float4(se2m, scem, sc2m, sm);
    __syncthreads();

    if (threadIdx.x == 0) {
        float4 s = red[0];
        #pragma unroll
        for (int w = 1; w < TPB / 64; ++w) {
            float4 r = red[w];
            s.x += r.x; s.y += r.y; s.z += r.z; s.w += r.w;
        }
        partials[(size_t)ch * BPC + bin] = s;
    }
}

// Kernel 2: reduce BPC partials per channel, apply alpha/err formula, reduce
// over all 48 channels to the scalar loss.
__global__ __launch_bounds__(64) void smse_final(
    const float4* __restrict__ partials,
    float* __restrict__ out)
{
    const int t = threadIdx.x;  // 64 threads, one wave
    float val = 0.f;
    if (t < NCH) {
        double v = 0.0, num = 0.0, cc = 0.0, ms = 0.0;
        for (int b = 0; b < BPC; ++b) {
            float4 p = partials[(size_t)t * BPC + b];
            v   += p.x;
            num += p.y;
            cc  += p.z;
            ms  += p.w;
        }
        double alpha = (v > V_EPS) ? (num / v) : 0.0;
        double err = cc - alpha * (2.0 * num - alpha * v);
        val = (float)(err / ms);
    }
    #pragma unroll
    for (int off = 32; off > 0; off >>= 1) val += __shfl_down(val, off);
    if (t == 0) out[0] = val / (float)NCH;
}

extern "C" void kernel_launch(void* const* d_in, const int* in_sizes, int n_in,
                              void* d_out, int out_size, void* d_ws, size_t ws_size,
                              hipStream_t stream) {
    const float* correct  = (const float*)d_in[0];
    const float* estimate = (const float*)d_in[1];
    const float* mask     = (const float*)d_in[2];
    float* out = (float*)d_out;
    float4* partials = (float4*)d_ws;  // NCH*BPC float4 = 24 KiB

    smse_partials<<<NCH * BPC, TPB, 0, stream>>>(correct, estimate, mask, partials);
    smse_final<<<1, 64, 0, stream>>>(partials, out);
}